// Round 3
// baseline (494.800 us; speedup 1.0000x reference)
//
#include <hip/hip_runtime.h>

typedef __attribute__((ext_vector_type(8))) short short8;
typedef __attribute__((ext_vector_type(4))) float floatx4;

constexpr int kS = 2048, kH = 16, kD = 64;
constexpr int kBatch = 4;
constexpr float kScale = 0.125f;   // 1/sqrt(64)
constexpr int LSTR = 72;           // LDS row stride in bf16 elems (16B-aligned rows, 4-bank row shift)

__device__ inline unsigned short f2bf(float x) {  // RNE fp32 -> bf16
  unsigned u = __float_as_uint(x);
  u += 0x7fffu + ((u >> 16) & 1u);
  return (unsigned short)(u >> 16);
}

__device__ inline unsigned cvt_pk_bf16(float lo, float hi) {  // lo -> bits[15:0], hi -> bits[31:16], RNE
  unsigned r;
  asm("v_cvt_pk_bf16_f32 %0, %1, %2" : "=v"(r) : "v"(lo), "v"(hi));
  return r;
}

// ---------------- pre-pass: fp32 [B,S,H,D] -> bf16 Qb/Kb [B,H,S,D], Vt [B,H,D,S] ----
__global__ __launch_bounds__(256) void prepass_kernel(
    const float* __restrict__ Q, const float* __restrict__ K,
    const float* __restrict__ V, unsigned short* __restrict__ Qb,
    unsigned short* __restrict__ Kb, unsigned short* __restrict__ Vt) {
  __shared__ unsigned short vs[64 * LSTR];
  const int t = threadIdx.x;
  const int st = blockIdx.x, h = blockIdx.y, b = blockIdx.z;
  const int bh = b * kH + h;
  const int r = t >> 2, c = (t & 3) * 16;
  const int s = st * 64 + r;
  const size_t in_off = ((size_t)(b * kS + s) * kH + h) * kD + c;
  const size_t qk_out = ((size_t)bh * kS + s) * kD + c;

  unsigned short tmp[16];
  {
    const float4* ip = (const float4*)(Q + in_off);
#pragma unroll
    for (int i = 0; i < 4; ++i) {
      float4 f = ip[i];
      tmp[i*4+0]=f2bf(f.x); tmp[i*4+1]=f2bf(f.y); tmp[i*4+2]=f2bf(f.z); tmp[i*4+3]=f2bf(f.w);
    }
    *(uint4*)(Qb + qk_out) = *(const uint4*)&tmp[0];
    *(uint4*)(Qb + qk_out + 8) = *(const uint4*)&tmp[8];
  }
  {
    const float4* ip = (const float4*)(K + in_off);
#pragma unroll
    for (int i = 0; i < 4; ++i) {
      float4 f = ip[i];
      tmp[i*4+0]=f2bf(f.x); tmp[i*4+1]=f2bf(f.y); tmp[i*4+2]=f2bf(f.z); tmp[i*4+3]=f2bf(f.w);
    }
    *(uint4*)(Kb + qk_out) = *(const uint4*)&tmp[0];
    *(uint4*)(Kb + qk_out + 8) = *(const uint4*)&tmp[8];
  }
  {
    const float4* ip = (const float4*)(V + in_off);
#pragma unroll
    for (int i = 0; i < 4; ++i) {
      float4 f = ip[i];
      tmp[i*4+0]=f2bf(f.x); tmp[i*4+1]=f2bf(f.y); tmp[i*4+2]=f2bf(f.z); tmp[i*4+3]=f2bf(f.w);
    }
    *(uint4*)&vs[r * LSTR + c] = *(const uint4*)&tmp[0];
    *(uint4*)&vs[r * LSTR + c + 8] = *(const uint4*)&tmp[8];
  }
  __syncthreads();
  // transposed write: thread t owns dim d = r, key cols st*64 + c .. +15
  unsigned short tv[16];
#pragma unroll
  for (int i = 0; i < 16; ++i) tv[i] = vs[(c + i) * LSTR + r];
  const size_t vt_out = ((size_t)bh * kD + r) * kS + st * 64 + c;
  *(uint4*)(Vt + vt_out) = *(const uint4*)&tv[0];
  *(uint4*)(Vt + vt_out + 8) = *(const uint4*)&tv[8];
}

// ---------------- main flash-attention kernel ----------------
// Q-tile = 128 rows, 4 waves x 32 q-rows (2 groups of 16). K/V LDS fragments are
// read ONCE per wave and feed BOTH q-groups' MFMAs -> LDS-pipe cycles per unit of
// work halve (the measured bottleneck). k-tile-iters per bh drop 528 -> 272, so
// bias/K/V logical memory traffic also halves.
// Swapped QK^T (K as A-operand): lane holds q-row l16, 4 consecutive k-cols.
// K/V double-buffered in LDS -> ONE barrier per k-tile. Fixed-max softmax.
// XCD swizzle: xcd = h&7 (2 heads/XCD, balanced), qt DESC, {b,h2} fastest.
__global__ __launch_bounds__(256, 2) void fa_mfma_kernel(
    const unsigned short* __restrict__ Qb, const unsigned short* __restrict__ Kb,
    const unsigned short* __restrict__ Vt, const float* __restrict__ Bias,
    float* __restrict__ O) {
  __shared__ unsigned short Ks[2][64 * LSTR];
  __shared__ unsigned short Vs[2][64 * LSTR];
  __shared__ unsigned short Ps[128 * LSTR];  // per-wave 32 rows, wave-private

  const int t = threadIdx.x;
  const int lane = t & 63, w = t >> 6;
  const int quad = lane >> 4, l16 = lane & 15;

  // ---- XCD swizzle: physical p -> (xcd = p&7, rank r = p>>3) ----
  const int p = blockIdx.x;
  const int xcd = p & 7;
  const int r = p >> 3;               // 0..127 within this XCD
  const int qt = 15 - (r >> 3);       // qt descending: longest blocks first
  const int b = (r >> 1) & 3;
  const int h = ((r & 1) << 3) | xcd; // each XCD owns heads {xcd, xcd+8}
  const int bh = b * kH + h;

  const int sr = t >> 2, sc = (t & 3) * 16;  // staging row / col (bf16 elems)

  const int qr0 = qt * 128 + w * 32 + l16;   // q-row of group 0; group 1 = +16

  // ---- Q fragments straight from global ----
  short8 aQ[2][2];
#pragma unroll
  for (int qg = 0; qg < 2; ++qg) {
    const unsigned short* qp = Qb + ((size_t)bh * kS + qr0 + qg * 16) * kD + quad * 8;
    aQ[qg][0] = *(const short8*)qp;
    aQ[qg][1] = *(const short8*)(qp + 32);
  }

  unsigned short* Psw = Ps + w * 32 * LSTR;

  floatx4 acc[2][4];
#pragma unroll
  for (int qg = 0; qg < 2; ++qg)
#pragma unroll
    for (int i = 0; i < 4; ++i) acc[qg][i] = (floatx4){0.f, 0.f, 0.f, 0.f};
  float lp[2] = {0.f, 0.f};

  const float* bp[2];
#pragma unroll
  for (int qg = 0; qg < 2; ++qg)
    bp[qg] = Bias + (size_t)h * kS * kS + (size_t)(qr0 + qg * 16) * kS + quad * 4;
  const unsigned short* Kbh = Kb + (size_t)bh * kS * kD;
  const unsigned short* Vbh = Vt + (size_t)bh * kD * kS;

  const int nkb = 2 * qt + 2;         // k-tiles to process (always even)
  const int wmax = qt * 128 + w * 32 + 31;  // max q-row this wave owns

  uint4 kr0, kr1, vr0, vr1;
  float4 bbA[8], bbB[8];              // [qg*4+nt] bias stage for even/odd k-tiles

  // ---- tile 0 -> LDS[0]; prefetch tile 1 into regs; stage bias tiles 0,1 ----
  {
    const uint4* srck = (const uint4*)(Kbh + (size_t)sr * kD + sc);
    kr0 = srck[0]; kr1 = srck[1];
    const uint4* srcv = (const uint4*)(Vbh + (size_t)sr * kS + sc);
    vr0 = srcv[0]; vr1 = srcv[1];
  }
#pragma unroll
  for (int qg = 0; qg < 2; ++qg)
#pragma unroll
    for (int nt = 0; nt < 4; ++nt) bbA[qg * 4 + nt] = *(const float4*)(bp[qg] + nt * 16);
  *(uint4*)&Ks[0][sr * LSTR + sc] = kr0;
  *(uint4*)&Ks[0][sr * LSTR + sc + 8] = kr1;
  *(uint4*)&Vs[0][sr * LSTR + sc] = vr0;
  *(uint4*)&Vs[0][sr * LSTR + sc + 8] = vr1;
  {
    const uint4* srck = (const uint4*)(Kbh + (size_t)(64 + sr) * kD + sc);
    kr0 = srck[0]; kr1 = srck[1];
    const uint4* srcv = (const uint4*)(Vbh + (size_t)sr * kS + 64 + sc);
    vr0 = srcv[0]; vr1 = srcv[1];
#pragma unroll
    for (int qg = 0; qg < 2; ++qg)
#pragma unroll
      for (int nt = 0; nt < 4; ++nt) bbB[qg * 4 + nt] = *(const float4*)(bp[qg] + 64 + nt * 16);
  }
  __syncthreads();

  auto iter = [&](const int kb, const unsigned short* Kc, const unsigned short* Vc,
                  unsigned short* Kn, unsigned short* Vn, float4* bb) {
    const int k0 = kb * 64;
    const bool diag = (kb >= 2 * qt);
    const bool alive = !(diag && (k0 > wmax));  // wave-uniform: skip fully-masked iters

    if (alive) {
      // ---- QK^T: K-frags read once, feed both q-groups ----
#pragma unroll
      for (int nt = 0; nt < 4; ++nt) {
        short8 a0 = *(const short8*)&Kc[(nt * 16 + l16) * LSTR + quad * 8];
        short8 a1 = *(const short8*)&Kc[(nt * 16 + l16) * LSTR + quad * 8 + 32];
        floatx4 cf[2];
#pragma unroll
        for (int qg = 0; qg < 2; ++qg) {
          floatx4 c0 = (floatx4){0.f, 0.f, 0.f, 0.f};
          c0 = __builtin_amdgcn_mfma_f32_16x16x32_bf16(a0, aQ[qg][0], c0, 0, 0, 0);
          cf[qg] = __builtin_amdgcn_mfma_f32_16x16x32_bf16(a1, aQ[qg][1], c0, 0, 0, 0);
        }
        const int colb = k0 + nt * 16 + quad * 4;
#pragma unroll
        for (int qg = 0; qg < 2; ++qg) {
          const float* bf = (const float*)&bb[qg * 4 + nt];
          const int qrow = qr0 + qg * 16;
          float p4[4];
#pragma unroll
          for (int reg = 0; reg < 4; ++reg) {
            const float x = cf[qg][reg] * kScale + bf[reg];
            float pv = __expf(x);
            if (diag && (colb + reg > qrow)) pv = 0.f;
            p4[reg] = pv;
          }
          lp[qg] += (p4[0] + p4[1]) + (p4[2] + p4[3]);
          const unsigned u0 = cvt_pk_bf16(p4[0], p4[1]);
          const unsigned u1 = cvt_pk_bf16(p4[2], p4[3]);
          *(uint2*)&Psw[(qg * 16 + l16) * LSTR + nt * 16 + quad * 4] = make_uint2(u0, u1);
        }
      }
    }

    // ---- stage next bias (bb consumed above); only needed while kb+2 exists ----
    if (kb + 2 < nkb) {
      const int kn = k0 + 128;
#pragma unroll
      for (int qg = 0; qg < 2; ++qg)
#pragma unroll
        for (int nt = 0; nt < 4; ++nt)
          bb[qg * 4 + nt] = *(const float4*)(bp[qg] + kn + nt * 16);
    }

    if (alive) {
      // ---- PV: V-frags read once, feed both q-groups ----
#pragma unroll
      for (int ks = 0; ks < 2; ++ks) {
        short8 aP0 = *(const short8*)&Psw[l16 * LSTR + ks * 32 + quad * 8];
        short8 aP1 = *(const short8*)&Psw[(16 + l16) * LSTR + ks * 32 + quad * 8];
#pragma unroll
        for (int dt = 0; dt < 4; ++dt) {
          short8 bV = *(const short8*)&Vc[(dt * 16 + l16) * LSTR + ks * 32 + quad * 8];
          acc[0][dt] = __builtin_amdgcn_mfma_f32_16x16x32_bf16(aP0, bV, acc[0][dt], 0, 0, 0);
          acc[1][dt] = __builtin_amdgcn_mfma_f32_16x16x32_bf16(aP1, bV, acc[1][dt], 0, 0, 0);
        }
      }
    }

    if (kb + 1 < nkb) {
      // stage tile kb+1 (regs a full iteration old -> vmcnt wait off critical path)
      *(uint4*)&Kn[sr * LSTR + sc] = kr0;
      *(uint4*)&Kn[sr * LSTR + sc + 8] = kr1;
      *(uint4*)&Vn[sr * LSTR + sc] = vr0;
      *(uint4*)&Vn[sr * LSTR + sc + 8] = vr1;
      if (kb + 2 < nkb) {
        const int kn = k0 + 128;
        const uint4* srck = (const uint4*)(Kbh + (size_t)(kn + sr) * kD + sc);
        kr0 = srck[0]; kr1 = srck[1];
        const uint4* srcv = (const uint4*)(Vbh + (size_t)sr * kS + kn + sc);
        vr0 = srcv[0]; vr1 = srcv[1];
      }
      __syncthreads();  // single barrier per k-tile
    }
  };

  for (int kb = 0; kb < nkb; kb += 2) {
    iter(kb, Ks[0], Vs[0], Ks[1], Vs[1], bbA);
    iter(kb + 1, Ks[1], Vs[1], Ks[0], Vs[0], bbB);
  }

  // ---- epilogue ----
#pragma unroll
  for (int qg = 0; qg < 2; ++qg) {
    float l = lp[qg];
    l += __shfl_xor(l, 16, 64);
    l += __shfl_xor(l, 32, 64);
    const float linv = 1.f / l;
#pragma unroll
    for (int reg = 0; reg < 4; ++reg) {
      const float il = __shfl(linv, quad * 4 + reg, 16);
      float* op = O + ((size_t)(b * kS + qt * 128 + w * 32 + qg * 16 + quad * 4 + reg) * kH + h) * kD;
#pragma unroll
      for (int dt = 0; dt < 4; ++dt)
        op[dt * 16 + l16] = acc[qg][dt][reg] * il;
    }
  }
}

extern "C" void kernel_launch(void* const* d_in, const int* in_sizes, int n_in,
                              void* d_out, int out_size, void* d_ws, size_t ws_size,
                              hipStream_t stream) {
  const float* q = (const float*)d_in[0];
  const float* k = (const float*)d_in[1];
  const float* v = (const float*)d_in[2];
  const float* bias = (const float*)d_in[3];
  float* out = (float*)d_out;

  const size_t elems = (size_t)kBatch * kH * kS * kD;  // 8,388,608
  unsigned short* Qb = (unsigned short*)d_ws;
  unsigned short* Kb = Qb + elems;
  unsigned short* Vt = Kb + elems;

  dim3 pgrid(kS / 64, kH, kBatch);  // (32, 16, 4)
  prepass_kernel<<<pgrid, dim3(256), 0, stream>>>(q, k, v, Qb, Kb, Vt);
  fa_mfma_kernel<<<dim3((kS / 128) * kH * kBatch), dim3(256), 0, stream>>>(Qb, Kb, Vt, bias, out);
}

// Round 4
// 478.624 us; speedup vs baseline: 1.0338x; 1.0338x over previous
//
#include <hip/hip_runtime.h>

typedef __attribute__((ext_vector_type(8))) short short8;
typedef __attribute__((ext_vector_type(4))) float floatx4;

constexpr int kS = 2048, kH = 16, kD = 64;
constexpr int kBatch = 4;
constexpr float kScale = 0.125f;   // 1/sqrt(64)
constexpr int LSTR = 72;           // LDS row stride in bf16 elems (16B-aligned rows, 4-bank row shift)

__device__ inline unsigned short f2bf(float x) {  // RNE fp32 -> bf16
  unsigned u = __float_as_uint(x);
  u += 0x7fffu + ((u >> 16) & 1u);
  return (unsigned short)(u >> 16);
}

__device__ inline unsigned cvt_pk_bf16(float lo, float hi) {  // lo -> bits[15:0], hi -> bits[31:16], RNE
  unsigned r;
  asm("v_cvt_pk_bf16_f32 %0, %1, %2" : "=v"(r) : "v"(lo), "v"(hi));
  return r;
}

// ---------------- pre-pass: fp32 K,V [B,S,H,D] -> bf16 Kb [B,H,S,D], Vt [B,H,D,S] ----
// (Q is converted in-register inside the fa kernel; no Qb workspace round-trip.)
__global__ __launch_bounds__(256) void prepass_kernel(
    const float* __restrict__ K, const float* __restrict__ V,
    unsigned short* __restrict__ Kb, unsigned short* __restrict__ Vt) {
  __shared__ unsigned short vs[64 * LSTR];
  const int t = threadIdx.x;
  const int st = blockIdx.x, h = blockIdx.y, b = blockIdx.z;
  const int bh = b * kH + h;
  const int r = t >> 2, c = (t & 3) * 16;
  const int s = st * 64 + r;
  const size_t in_off = ((size_t)(b * kS + s) * kH + h) * kD + c;
  const size_t qk_out = ((size_t)bh * kS + s) * kD + c;

  unsigned short tmp[16];
  {
    const float4* ip = (const float4*)(K + in_off);
#pragma unroll
    for (int i = 0; i < 4; ++i) {
      float4 f = ip[i];
      tmp[i*4+0]=f2bf(f.x); tmp[i*4+1]=f2bf(f.y); tmp[i*4+2]=f2bf(f.z); tmp[i*4+3]=f2bf(f.w);
    }
    *(uint4*)(Kb + qk_out) = *(const uint4*)&tmp[0];
    *(uint4*)(Kb + qk_out + 8) = *(const uint4*)&tmp[8];
  }
  {
    const float4* ip = (const float4*)(V + in_off);
#pragma unroll
    for (int i = 0; i < 4; ++i) {
      float4 f = ip[i];
      tmp[i*4+0]=f2bf(f.x); tmp[i*4+1]=f2bf(f.y); tmp[i*4+2]=f2bf(f.z); tmp[i*4+3]=f2bf(f.w);
    }
    *(uint4*)&vs[r * LSTR + c] = *(const uint4*)&tmp[0];
    *(uint4*)&vs[r * LSTR + c + 8] = *(const uint4*)&tmp[8];
  }
  __syncthreads();
  // transposed write: thread t owns dim d = r, key cols st*64 + c .. +15
  unsigned short tv[16];
#pragma unroll
  for (int i = 0; i < 16; ++i) tv[i] = vs[(c + i) * LSTR + r];
  const size_t vt_out = ((size_t)bh * kD + r) * kS + st * 64 + c;
  *(uint4*)(Vt + vt_out) = *(const uint4*)&tv[0];
  *(uint4*)(Vt + vt_out + 8) = *(const uint4*)&tv[8];
}

// ---------------- main flash-attention kernel ----------------
// R2 structure (best measured): Q-tile 64, 4 waves x 16 q-rows, 3 blocks/CU,
// K/V double-buffered in LDS -> ONE barrier per k-tile, fixed-max softmax,
// swapped QK^T (K as A-operand: lane owns q-row l16, 4 consecutive k-cols).
// Q is read from the fp32 input and converted to bf16 fragments in-register
// (one-time per block; kills the Qb DRAM round-trip).
// XCD swizzle: xcd = h&7 (2 heads/XCD, balanced), qt DESC, {b,h2} fastest.
__global__ __launch_bounds__(256, 3) void fa_mfma_kernel(
    const float* __restrict__ Q, const unsigned short* __restrict__ Kb,
    const unsigned short* __restrict__ Vt, const float* __restrict__ Bias,
    float* __restrict__ O) {
  __shared__ unsigned short Ks[2][64 * LSTR];
  __shared__ unsigned short Vs[2][64 * LSTR];
  __shared__ unsigned short Ps[64 * LSTR];  // per-wave P tiles (wave-private 16 rows each)

  const int t = threadIdx.x;
  const int lane = t & 63, w = t >> 6;
  const int quad = lane >> 4, l16 = lane & 15;

  // ---- XCD swizzle: physical p -> (xcd = p&7, rank r = p>>3) ----
  const int p = blockIdx.x;
  const int xcd = p & 7;
  const int r = p >> 3;               // 0..255 within this XCD
  const int qt = 31 - (r >> 3);       // qt descending: longest blocks first
  const int b = (r >> 1) & 3;
  const int h = ((r & 1) << 3) | xcd; // each XCD owns heads {xcd, xcd+8}
  const int bh = b * kH + h;

  const int sr = t >> 2, sc = (t & 3) * 16;  // staging row / col (bf16 elems)

  const int qrow = qt * 64 + w * 16 + l16;   // this lane's global q-row

  // ---- Q fragments: fp32 global -> bf16 regs (once per block) ----
  short8 aQ[2];
  {
    const float* qp = Q + ((size_t)(b * kS + qrow) * kH + h) * kD + quad * 8;
    float4 f0 = *(const float4*)qp;
    float4 f1 = *(const float4*)(qp + 4);
    float4 f2 = *(const float4*)(qp + 32);
    float4 f3 = *(const float4*)(qp + 36);
    unsigned short q8[16];
    q8[0] = f2bf(f0.x); q8[1] = f2bf(f0.y); q8[2] = f2bf(f0.z); q8[3] = f2bf(f0.w);
    q8[4] = f2bf(f1.x); q8[5] = f2bf(f1.y); q8[6] = f2bf(f1.z); q8[7] = f2bf(f1.w);
    q8[8]  = f2bf(f2.x); q8[9]  = f2bf(f2.y); q8[10] = f2bf(f2.z); q8[11] = f2bf(f2.w);
    q8[12] = f2bf(f3.x); q8[13] = f2bf(f3.y); q8[14] = f2bf(f3.z); q8[15] = f2bf(f3.w);
    aQ[0] = *(const short8*)&q8[0];
    aQ[1] = *(const short8*)&q8[8];
  }

  unsigned short* Psw = Ps + w * 16 * LSTR;

  floatx4 acc[4];
#pragma unroll
  for (int i = 0; i < 4; ++i) acc[i] = (floatx4){0.f, 0.f, 0.f, 0.f};
  float lp = 0.f;

  const float* bp = Bias + (size_t)h * kS * kS + (size_t)qrow * kS + quad * 4;
  const unsigned short* Kbh = Kb + (size_t)bh * kS * kD;
  const unsigned short* Vbh = Vt + (size_t)bh * kD * kS;

  uint4 kr0, kr1, vr0, vr1;
  float4 bbA[4], bbB[4];

  // ---- tile 0: regs -> LDS[0]; prefetch tile 1 into regs ----
  {
    const uint4* srck = (const uint4*)(Kbh + (size_t)sr * kD + sc);
    kr0 = srck[0]; kr1 = srck[1];
    const uint4* srcv = (const uint4*)(Vbh + (size_t)sr * kS + sc);
    vr0 = srcv[0]; vr1 = srcv[1];
  }
#pragma unroll
  for (int nt = 0; nt < 4; ++nt) bbA[nt] = *(const float4*)(bp + nt * 16);
  *(uint4*)&Ks[0][sr * LSTR + sc] = kr0;
  *(uint4*)&Ks[0][sr * LSTR + sc + 8] = kr1;
  *(uint4*)&Vs[0][sr * LSTR + sc] = vr0;
  *(uint4*)&Vs[0][sr * LSTR + sc + 8] = vr1;
  if (qt > 0) {
    const uint4* srck = (const uint4*)(Kbh + (size_t)(64 + sr) * kD + sc);
    kr0 = srck[0]; kr1 = srck[1];
    const uint4* srcv = (const uint4*)(Vbh + (size_t)sr * kS + 64 + sc);
    vr0 = srcv[0]; vr1 = srcv[1];
#pragma unroll
    for (int nt = 0; nt < 4; ++nt) bbB[nt] = *(const float4*)(bp + 64 + nt * 16);
  }
  __syncthreads();

  auto iter = [&](const int kb, const unsigned short* Kc, const unsigned short* Vc,
                  unsigned short* Kn, unsigned short* Vn, float4* bb) {
    const int k0 = kb * 64;
    const bool diag = (kb == qt);

    // ---- QK^T (swapped) -> score -> p = exp(score) -> pack bf16 -> LDS ----
#pragma unroll
    for (int nt = 0; nt < 4; ++nt) {
      short8 a0 = *(const short8*)&Kc[(nt * 16 + l16) * LSTR + quad * 8];
      short8 a1 = *(const short8*)&Kc[(nt * 16 + l16) * LSTR + quad * 8 + 32];
      floatx4 cf = (floatx4){0.f, 0.f, 0.f, 0.f};
      cf = __builtin_amdgcn_mfma_f32_16x16x32_bf16(a0, aQ[0], cf, 0, 0, 0);
      cf = __builtin_amdgcn_mfma_f32_16x16x32_bf16(a1, aQ[1], cf, 0, 0, 0);
      // cf[reg] = S[q = qrow][k = k0 + nt*16 + quad*4 + reg]
      const int colb = k0 + nt * 16 + quad * 4;
      const float* bf = (const float*)&bb[nt];
      float p4[4];
#pragma unroll
      for (int reg = 0; reg < 4; ++reg) {
        const float x = cf[reg] * kScale + bf[reg];
        float pv = __expf(x);
        if (diag && (colb + reg > qrow)) pv = 0.f;
        p4[reg] = pv;
      }
      lp += (p4[0] + p4[1]) + (p4[2] + p4[3]);
      const unsigned u0 = cvt_pk_bf16(p4[0], p4[1]);
      const unsigned u1 = cvt_pk_bf16(p4[2], p4[3]);
      *(uint2*)&Psw[l16 * LSTR + nt * 16 + quad * 4] = make_uint2(u0, u1);
    }

    // ---- PV (Psw row = q-row, cols = k) ----
#pragma unroll
    for (int ks = 0; ks < 2; ++ks) {
      short8 aP = *(const short8*)&Psw[l16 * LSTR + ks * 32 + quad * 8];
#pragma unroll
      for (int dt = 0; dt < 4; ++dt) {
        short8 bV = *(const short8*)&Vc[(dt * 16 + l16) * LSTR + ks * 32 + quad * 8];
        acc[dt] = __builtin_amdgcn_mfma_f32_16x16x32_bf16(aP, bV, acc[dt], 0, 0, 0);
      }
    }

    if (kb < qt) {
      // stage tile kb+1 (regs are a full iteration old -> vmcnt wait is free)
      *(uint4*)&Kn[sr * LSTR + sc] = kr0;
      *(uint4*)&Kn[sr * LSTR + sc + 8] = kr1;
      *(uint4*)&Vn[sr * LSTR + sc] = vr0;
      *(uint4*)&Vn[sr * LSTR + sc + 8] = vr1;
      // issue prefetch for tile kb+2 (regs freed by the ds_write above)
      if (kb + 1 < qt) {
        const int kn = k0 + 128;
        const uint4* srck = (const uint4*)(Kbh + (size_t)(kn + sr) * kD + sc);
        kr0 = srck[0]; kr1 = srck[1];
        const uint4* srcv = (const uint4*)(Vbh + (size_t)sr * kS + kn + sc);
        vr0 = srcv[0]; vr1 = srcv[1];
#pragma unroll
        for (int nt = 0; nt < 4; ++nt) bb[nt] = *(const float4*)(bp + kn + nt * 16);
      }
      __syncthreads();  // single barrier per k-tile
    }
  };

  for (int kb = 0; kb <= qt; kb += 2) {
    iter(kb, Ks[0], Vs[0], Ks[1], Vs[1], bbA);
    if (kb + 1 <= qt) iter(kb + 1, Ks[1], Vs[1], Ks[0], Vs[0], bbB);
  }

  // ---- epilogue: row-sums live per-lane for row l16; reduce across quads,
  //      then shuffle to the rows (quad*4+reg) this lane's acc covers ----
  lp += __shfl_xor(lp, 16, 64);
  lp += __shfl_xor(lp, 32, 64);
  const float linv = 1.f / lp;
#pragma unroll
  for (int reg = 0; reg < 4; ++reg) {
    const float il = __shfl(linv, quad * 4 + reg, 16);
    float* op = O + ((size_t)(b * kS + qt * 64 + w * 16 + quad * 4 + reg) * kH + h) * kD;
#pragma unroll
    for (int dt = 0; dt < 4; ++dt)
      op[dt * 16 + l16] = acc[dt][reg] * il;
  }
}

extern "C" void kernel_launch(void* const* d_in, const int* in_sizes, int n_in,
                              void* d_out, int out_size, void* d_ws, size_t ws_size,
                              hipStream_t stream) {
  const float* q = (const float*)d_in[0];
  const float* k = (const float*)d_in[1];
  const float* v = (const float*)d_in[2];
  const float* bias = (const float*)d_in[3];
  float* out = (float*)d_out;

  const size_t elems = (size_t)kBatch * kH * kS * kD;  // 8,388,608
  unsigned short* Kb = (unsigned short*)d_ws;
  unsigned short* Vt = Kb + elems;

  dim3 pgrid(kS / 64, kH, kBatch);  // (32, 16, 4)
  prepass_kernel<<<pgrid, dim3(256), 0, stream>>>(k, v, Kb, Vt);
  fa_mfma_kernel<<<dim3(32 * kH * kBatch), dim3(256), 0, stream>>>(q, Kb, Vt, bias, out);
}